// Round 5
// baseline (2992.516 us; speedup 1.0000x reference)
//
#include <hip/hip_runtime.h>
#include <hip/hip_bf16.h>

#define DEV __device__ __forceinline__

typedef unsigned short u16;
typedef unsigned int u32;

constexpr float INV_C  = 0.17677669529663687f;   // 1/sqrt(32)
constexpr float INV_S3 = 0.5773502691896258f;    // 1/sqrt(3)

DEV float bf2f(u32 h) { return __uint_as_float(h << 16); }
DEV u32 f2bf_bits(float f) {
  u32 u = __float_as_uint(f);
  u += 0x7fffu + ((u >> 16) & 1u);
  return u >> 16;
}

DEV void ld32f(const float* __restrict__ p, float o[32]) {
#pragma unroll
  for (int i = 0; i < 8; ++i) {
    float4 q = reinterpret_cast<const float4*>(p)[i];
    o[4*i+0]=q.x; o[4*i+1]=q.y; o[4*i+2]=q.z; o[4*i+3]=q.w;
  }
}
DEV void st32f(float* __restrict__ p, const float o[32]) {
#pragma unroll
  for (int i = 0; i < 8; ++i) {
    float4 q; q.x=o[4*i+0]; q.y=o[4*i+1]; q.z=o[4*i+2]; q.w=o[4*i+3];
    reinterpret_cast<float4*>(p)[i] = q;
  }
}
DEV void ld32h(const u16* __restrict__ p, float o[32]) {
#pragma unroll
  for (int i = 0; i < 4; ++i) {
    uint4 q = reinterpret_cast<const uint4*>(p)[i];
    u32 w0=q.x, w1=q.y, w2=q.z, w3=q.w;
    o[8*i+0]=bf2f(w0 & 0xffffu); o[8*i+1]=bf2f(w0 >> 16);
    o[8*i+2]=bf2f(w1 & 0xffffu); o[8*i+3]=bf2f(w1 >> 16);
    o[8*i+4]=bf2f(w2 & 0xffffu); o[8*i+5]=bf2f(w2 >> 16);
    o[8*i+6]=bf2f(w3 & 0xffffu); o[8*i+7]=bf2f(w3 >> 16);
  }
}
DEV void st32h(u16* __restrict__ p, const float o[32]) {
#pragma unroll
  for (int i = 0; i < 16; ++i) {
    reinterpret_cast<u32*>(p)[i] = f2bf_bits(o[2*i]) | (f2bf_bits(o[2*i+1]) << 16);
  }
}

template<bool BF>
DEV void ld_scr(const void* __restrict__ ws, size_t off, float o[32]) {
  if (BF) ld32h((const u16*)ws + off, o);
  else    ld32f((const float*)ws + off, o);
}
template<bool BF>
DEV void st_scr(void* __restrict__ ws, size_t off, const float v[32]) {
  if (BF) st32h((u16*)ws + off, v);
  else    st32f((float*)ws + off, v);
}

// out[d] (+)= INV_C * sum_c in[c] * W[c*32+d]
template<bool ACC>
DEV void linT(const float* __restrict__ W, const float in[32], float out[32]) {
  float acc[32];
#pragma unroll
  for (int d = 0; d < 32; ++d) acc[d] = 0.f;
#pragma unroll 4
  for (int c = 0; c < 32; ++c) {
    const float ic = in[c];
#pragma unroll
    for (int d = 0; d < 32; ++d) acc[d] = __builtin_fmaf(ic, W[c*32+d], acc[d]);
  }
#pragma unroll
  for (int d = 0; d < 32; ++d) out[d] = ACC ? __builtin_fmaf(acc[d], INV_C, out[d]) : acc[d]*INV_C;
}
// out[u] = INV_C * sum_v in[v] * W[u*32+v]
DEV void linN(const float* __restrict__ W, const float in[32], float out[32]) {
#pragma unroll 4
  for (int u = 0; u < 32; ++u) {
    float a = 0.f;
#pragma unroll
    for (int v = 0; v < 32; ++v) a = __builtin_fmaf(in[v], W[u*32+v], a);
    out[u] = a * INV_C;
  }
}

DEV float sigmoidf(float x) { return 1.f / (1.f + __expf(-x)); }

// Resblock, wave0 = scalar row, waves1..3 = vector comps. Gate via padded LDS.
// Internal 2-barrier structure: wave0's gsh write happens only after ALL threads
// pass barrier #1, so gsh may alias buffers whose last read precedes the call.
DEV void resblock_g(int wave, int lane, const float* __restrict__ W7,
                    const float in[32], float out[32], float* gsh) {
  float t1[32];
  linT<false>(W7 + (wave==0 ? 0 : 1)*1024, in, t1);     // s1 / v1
  linT<false>(W7 + (wave==0 ? 5 : 6)*1024, in, out);    // skip (in dies here)
  __syncthreads();                                      // barrier #1
  float t2[32];
  if (wave == 0) {
    float g[32];
    linT<false>(W7 + 2*1024, t1, g);                    // gate pre-act
#pragma unroll
    for (int c = 0; c < 32; ++c) gsh[lane*33+c] = sigmoidf(g[c]);
#pragma unroll
    for (int c = 0; c < 32; ++c) t2[c] = t1[c] * sigmoidf(t1[c]);   // silu
  }
  __syncthreads();                                      // barrier #2
  if (wave != 0) {
#pragma unroll
    for (int c = 0; c < 32; ++c) t2[c] = t1[c] * gsh[lane*33+c];
  }
  linT<true>(W7 + (wave==0 ? 3 : 4)*1024, t2, out);     // lin2 accumulate
}

// read one staged 32-float row (stride-34: 2-way bank aliasing = free)
DEV void rdrow(const float* buf, int lane, float o[32]) {
#pragma unroll
  for (int i = 0; i < 16; ++i) {
    float2 q = *reinterpret_cast<const float2*>(&buf[lane*34 + 2*i]);
    o[2*i] = q.x; o[2*i+1] = q.y;
  }
}

// ====================== node kernel (unchanged from round 3/4) ======================
template<bool BF>
__global__ __launch_bounds__(256, 2) void node_kernel(
    const float* __restrict__ node_s, const float* __restrict__ node_v,
    const float* __restrict__ tpw, const float* __restrict__ resw,
    void* __restrict__ wsN,
    float* __restrict__ dgs, float* __restrict__ dgv, int N)
{
  __shared__ float comm[6336];
  float* gsh = comm;
  const int lane = threadIdx.x & 63;
  const int wave = threadIdx.x >> 6;
  const int nblk = blockIdx.x * 64;
  const int n = nblk + lane;
  const bool active = n < N;
  const int nrows = (N - nblk < 64) ? (N - nblk) : 64;

  const float* Wtp0 = tpw;
  const float* Wtp1 = tpw + 4096;

  {
    const float4* s4 = reinterpret_cast<const float4*>(node_v + (size_t)nblk*96);
    int tot4 = nrows * 24;
    for (int i = threadIdx.x; i < tot4; i += 256) {
      int node = (4*i)/96; int r = 4*i - node*96;
      float4 q = s4[i];
      float* dp = &comm[node*97 + r];
      dp[0]=q.x; dp[1]=q.y; dp[2]=q.z; dp[3]=q.w;
    }
  }
  __syncthreads();

  float feat[32];
  if (wave == 0) {
    if (active) ld32f(node_s + (size_t)n*32, feat);
    else {
#pragma unroll
      for (int c = 0; c < 32; ++c) feat[c] = 0.f;
    }
  } else {
    const int x = wave - 1;
    if (active) {
#pragma unroll
      for (int c = 0; c < 32; ++c) feat[c] = comm[lane*97 + 3*c + x];
    } else {
#pragma unroll
      for (int c = 0; c < 32; ++c) feat[c] = 0.f;
    }
  }
  __syncthreads();

  float dsv[32];
  resblock_g(wave, lane, resw + 3*7168, feat, dsv, gsh);
  __syncthreads();

  float tpo[32];
  if (wave != 0) {
    const int x = wave - 1;
    float vr1[32];
    linN(Wtp0 + 1*1024, feat, vr1);
#pragma unroll
    for (int c = 0; c < 32; ++c) comm[x*2112 + lane*33 + c] = dsv[c]*vr1[c];
  }
  __syncthreads();
  if (wave == 0) {
    float sr0[32];
    linN(Wtp0 + 0*1024, feat, sr0);
#pragma unroll
    for (int c = 0; c < 32; ++c) {
      float a = comm[0*2112+lane*33+c] + comm[1*2112+lane*33+c] + comm[2*2112+lane*33+c];
      tpo[c] = dsv[c]*sr0[c] + a*INV_S3;
    }
    float sr3[32];
    linN(Wtp0 + 3*1024, feat, sr3);
#pragma unroll
    for (int c = 0; c < 32; ++c) comm[0*2112+lane*33+c] = dsv[c];
#pragma unroll
    for (int c = 0; c < 32; ++c) comm[1*2112+lane*33+c] = sr3[c];
  }
  __syncthreads();
  if (wave != 0) {
    float vr2[32];
    linN(Wtp0 + 2*1024, feat, vr2);
#pragma unroll
    for (int c = 0; c < 32; ++c)
      tpo[c] = comm[lane*33+c]*vr2[c] + dsv[c]*comm[2112+lane*33+c];
  }

  float eo[32];
  resblock_g(wave, lane, resw + 4*7168, tpo, eo, gsh);
  {
    float qo[32];
    resblock_g(wave, lane, resw + 5*7168, feat, qo, gsh);
#pragma unroll
    for (int c = 0; c < 32; ++c) eo[c] += qo[c];
  }
  __syncthreads();

  if (wave == 0) {
    if (active) st32f(dgs + (size_t)n*32, eo);
  } else {
    const int x = wave - 1;
#pragma unroll
    for (int c = 0; c < 32; ++c) comm[lane*97 + 3*c + x] = eo[c];
  }
  __syncthreads();
  {
    float4* d4 = reinterpret_cast<float4*>(dgv + (size_t)nblk*96);
    int tot4 = nrows * 24;
    for (int i = threadIdx.x; i < tot4; i += 256) {
      int node = (4*i)/96; int r = 4*i - node*96;
      const float* sp = &comm[node*97 + r];
      float4 q; q.x=sp[0]; q.y=sp[1]; q.z=sp[2]; q.w=sp[3];
      d4[i] = q;
    }
  }

  const size_t base = (size_t)n * 512;
  {
    float ao[32];
    resblock_g(wave, lane, resw + 0*7168, feat, ao, gsh);
    if (active) {
      if (wave == 0) st_scr<BF>(wsN, base + 0, ao);
      else           st_scr<BF>(wsN, base + 32 + (size_t)(wave-1)*32, ao);
    }
  }
  {
    float ao[32];
    resblock_g(wave, lane, resw + 2*7168, feat, ao, gsh);
    if (active) {
      if (wave == 0) st_scr<BF>(wsN, base + 128, ao);
      else           st_scr<BF>(wsN, base + 160 + (size_t)(wave-1)*32, ao);
    }
  }
  {
    float b[32];
    if (wave == 0) {
      linN(Wtp1 + 0*1024, feat, b);
      if (active) st_scr<BF>(wsN, base + 256, b);
      linN(Wtp1 + 3*1024, feat, b);
      if (active) st_scr<BF>(wsN, base + 480, b);
    } else {
      const size_t x = wave - 1;
      linN(Wtp1 + 1*1024, feat, b);
      if (active) st_scr<BF>(wsN, base + 288 + x*32, b);
      linN(Wtp1 + 2*1024, feat, b);
      if (active) st_scr<BF>(wsN, base + 384 + x*32, b);
    }
  }
}

// ====================== edge kernel: coalesced staged gather ======================
// Thread t loads 32B of row (edge=t/4, part=t%4): 4 consecutive lanes cover one
// 128B row contiguously -> coalesced. Double-buffered [64][34] LDS tiles, 2-deep
// register prefetch (issue stage s+2 while consuming stage s), 1 barrier/stage.
#define EK_PREF(P0, P1, base, off) { \
  const float4* _p = reinterpret_cast<const float4*>((base) + (off)); \
  P0 = _p[0]; P1 = _p[1]; }
#define EK_STG(bufofs, P0, P1) { \
  float* _q = &smem[(bufofs) + le*34 + lp*8]; \
  reinterpret_cast<float2*>(_q)[0] = make_float2(P0.x, P0.y); \
  reinterpret_cast<float2*>(_q)[1] = make_float2(P0.z, P0.w); \
  reinterpret_cast<float2*>(_q)[2] = make_float2(P1.x, P1.y); \
  reinterpret_cast<float2*>(_q)[3] = make_float2(P1.z, P1.w); }

__global__ __launch_bounds__(256, 4) void edge_kernel_f32(
    const int* __restrict__ ei, const float* __restrict__ resw,
    const float* __restrict__ wsN,
    float* __restrict__ offs, float* __restrict__ offv, int E)
{
  __shared__ float smem[4352];   // 2 stage bufs [64][34] / gate [64][33] / outstage [32][97]
  __shared__ int eidx[128];      // [0..63]=src, [64..127]=dst
  const int tid  = threadIdx.x;
  const int lane = tid & 63;
  const int wave = tid >> 6;
  const int eblk = blockIdx.x * 64;
  const bool active = (eblk + lane) < E;
  const int erows = (E - eblk < 64) ? (E - eblk) : 64;

  if (tid < 128) {
    int e = eblk + (tid & 63); if (e >= E) e = E - 1;
    eidx[tid] = (tid < 64) ? ei[e] : ei[(size_t)E + e];
  }
  __syncthreads();

  const int le = tid >> 2, lp = tid & 3;
  const float* sb = wsN + (size_t)eidx[le] * 512 + lp * 8;
  const float* db = wsN + (size_t)eidx[64 + le] * 512 + lp * 8;

  float4 Pa0, Pa1, Pb0, Pb1;
  float a0[32], av[32], t[32], w[32];

  EK_PREF(Pa0, Pa1, db, 0);          // s0: A_s
  EK_PREF(Pb0, Pb1, sb, 256);        // s1: B0

  // s0: A_s -> buf0; all waves keep a0
  EK_STG(0, Pa0, Pa1);  EK_PREF(Pa0, Pa1, sb, 384);   // s2: Vr2_0
  __syncthreads();
  rdrow(smem, lane, a0);

  // s1: B0 -> buf1; w0: t = a0*B0
  EK_STG(2176, Pb0, Pb1);  EK_PREF(Pb0, Pb1, sb, 416);   // s3: Vr2_1
  __syncthreads();
  if (wave == 0) {
    rdrow(smem + 2176, lane, w);
#pragma unroll
    for (int c = 0; c < 32; ++c) t[c] = a0[c]*w[c];
  }

  // s2: Vr2_0 -> buf0; w1: t = a0*Vr2_0
  EK_STG(0, Pa0, Pa1);  EK_PREF(Pa0, Pa1, sb, 448);   // s4: Vr2_2
  __syncthreads();
  if (wave == 1) {
    rdrow(smem, lane, w);
#pragma unroll
    for (int c = 0; c < 32; ++c) t[c] = a0[c]*w[c];
  }

  // s3: Vr2_1 -> buf1; w2: t = a0*Vr2_1
  EK_STG(2176, Pb0, Pb1);  EK_PREF(Pb0, Pb1, db, 32);   // s5: A_v0
  __syncthreads();
  if (wave == 2) {
    rdrow(smem + 2176, lane, w);
#pragma unroll
    for (int c = 0; c < 32; ++c) t[c] = a0[c]*w[c];
  }

  // s4: Vr2_2 -> buf0; w3: t = a0*Vr2_2
  EK_STG(0, Pa0, Pa1);  EK_PREF(Pa0, Pa1, sb, 288);   // s6: Vr1_0
  __syncthreads();
  if (wave == 3) {
    rdrow(smem, lane, w);
#pragma unroll
    for (int c = 0; c < 32; ++c) t[c] = a0[c]*w[c];
  }

  // s5: A_v0 -> buf1; w0: av = A_v0*IS3, w1: av = A_v0
  EK_STG(2176, Pb0, Pb1);  EK_PREF(Pb0, Pb1, db, 64);   // s7: A_v1
  __syncthreads();
  if (wave <= 1) {
    rdrow(smem + 2176, lane, w);
#pragma unroll
    for (int c = 0; c < 32; ++c) av[c] = (wave == 0) ? w[c]*INV_S3 : w[c];
  }

  // s6: Vr1_0 -> buf0; w0: t += av*Vr1_0
  EK_STG(0, Pa0, Pa1);  EK_PREF(Pa0, Pa1, sb, 320);   // s8: Vr1_1
  __syncthreads();
  if (wave == 0) {
    rdrow(smem, lane, w);
#pragma unroll
    for (int c = 0; c < 32; ++c) t[c] = __builtin_fmaf(av[c], w[c], t[c]);
  }

  // s7: A_v1 -> buf1; w0: av = A_v1*IS3, w2: av = A_v1
  EK_STG(2176, Pb0, Pb1);  EK_PREF(Pb0, Pb1, db, 96);   // s9: A_v2
  __syncthreads();
  if (wave == 0 || wave == 2) {
    rdrow(smem + 2176, lane, w);
#pragma unroll
    for (int c = 0; c < 32; ++c) av[c] = (wave == 0) ? w[c]*INV_S3 : w[c];
  }

  // s8: Vr1_1 -> buf0; w0: t += av*Vr1_1
  EK_STG(0, Pa0, Pa1);  EK_PREF(Pa0, Pa1, sb, 352);   // s10: Vr1_2
  __syncthreads();
  if (wave == 0) {
    rdrow(smem, lane, w);
#pragma unroll
    for (int c = 0; c < 32; ++c) t[c] = __builtin_fmaf(av[c], w[c], t[c]);
  }

  // s9: A_v2 -> buf1; w0: av = A_v2*IS3, w3: av = A_v2
  EK_STG(2176, Pb0, Pb1);  EK_PREF(Pb0, Pb1, sb, 480);   // s11: B3
  __syncthreads();
  if (wave == 0 || wave == 3) {
    rdrow(smem + 2176, lane, w);
#pragma unroll
    for (int c = 0; c < 32; ++c) av[c] = (wave == 0) ? w[c]*INV_S3 : w[c];
  }

  // s10: Vr1_2 -> buf0; w0: t += av*Vr1_2
  EK_STG(0, Pa0, Pa1);
  __syncthreads();
  if (wave == 0) {
    rdrow(smem, lane, w);
#pragma unroll
    for (int c = 0; c < 32; ++c) t[c] = __builtin_fmaf(av[c], w[c], t[c]);
  }

  // s11: B3 -> buf1; w1,w2,w3: t += av*B3
  EK_STG(2176, Pb0, Pb1);
  __syncthreads();
  if (wave != 0) {
    rdrow(smem + 2176, lane, w);
#pragma unroll
    for (int c = 0; c < 32; ++c) t[c] = __builtin_fmaf(av[c], w[c], t[c]);
  }
  // resblock barrier #1 orders the buf reads above vs. gate writes below

  float o[32];
  resblock_g(wave, lane, resw + 1*7168, t, o, smem);

  // R[dst] direct per-lane (only 4 rows/edge) + add + scalar store
  {
    const float* drow = wsN + (size_t)eidx[64 + lane] * 512;
    float r[32];
    if (wave == 0) {
      ld32f(drow + 128, r);
#pragma unroll
      for (int c = 0; c < 32; ++c) o[c] += r[c];
      if (active) st32f(offs + (size_t)(eblk + lane)*32, o);
    } else {
      ld32f(drow + 160 + (size_t)(wave - 1)*32, r);
#pragma unroll
      for (int c = 0; c < 32; ++c) o[c] += r[c];
    }
  }
  __syncthreads();   // gate reads done; smem reused as output staging

  const int half = lane >> 5;
  const int lrow = lane & 31;
  const int rows0 = (erows < 32) ? erows : 32;
  const int rows1 = erows - rows0;

  if (wave != 0 && half == 0) {
    const int x = wave - 1;
#pragma unroll
    for (int c = 0; c < 32; ++c) smem[lrow*97 + 3*c + x] = o[c];
  }
  __syncthreads();
  {
    float4* d4 = reinterpret_cast<float4*>(offv + (size_t)eblk*96);
    int tot4 = rows0 * 24;
    for (int i = threadIdx.x; i < tot4; i += 256) {
      int row = (4*i)/96; int r = 4*i - row*96;
      const float* sp = &smem[row*97 + r];
      float4 q; q.x=sp[0]; q.y=sp[1]; q.z=sp[2]; q.w=sp[3];
      d4[i] = q;
    }
  }
  __syncthreads();
  if (wave != 0 && half == 1) {
    const int x = wave - 1;
#pragma unroll
    for (int c = 0; c < 32; ++c) smem[lrow*97 + 3*c + x] = o[c];
  }
  __syncthreads();
  if (rows1 > 0) {
    float4* d4 = reinterpret_cast<float4*>(offv + ((size_t)eblk + 32)*96);
    int tot4 = rows1 * 24;
    for (int i = threadIdx.x; i < tot4; i += 256) {
      int row = (4*i)/96; int r = 4*i - row*96;
      const float* sp = &smem[row*97 + r];
      float4 q; q.x=sp[0]; q.y=sp[1]; q.z=sp[2]; q.w=sp[3];
      d4[i] = q;
    }
  }
}

// bf16-scratch fallback edge kernel (only if ws too small for f32 scratch)
__global__ __launch_bounds__(256, 2) void edge_kernel_bf(
    const int* __restrict__ ei, const float* __restrict__ resw,
    const void* __restrict__ wsN,
    float* __restrict__ offs, float* __restrict__ offv, int E)
{
  __shared__ float smem[3104];
  const int lane = threadIdx.x & 63;
  const int wave = threadIdx.x >> 6;
  const int eblk = blockIdx.x * 64;
  const int e = eblk + lane;
  const bool active = e < E;
  const int erows = (E - eblk < 64) ? (E - eblk) : 64;
  int src = 0, dst = 0;
  if (active) { src = ei[e]; dst = ei[E + e]; }
  const size_t bs = (size_t)src * 512;
  const size_t bd = (size_t)dst * 512;
  const float* Wres1 = resw + 1*7168;

  float t[32];
  if (wave == 0) {
    float a[32], b[32];
    ld_scr<true>(wsN, bd + 0, a);
    ld_scr<true>(wsN, bs + 256, b);
#pragma unroll
    for (int c = 0; c < 32; ++c) t[c] = a[c]*b[c];
#pragma unroll
    for (int x = 0; x < 3; ++x) {
      ld_scr<true>(wsN, bd + 32 + (size_t)x*32, a);
      ld_scr<true>(wsN, bs + 288 + (size_t)x*32, b);
#pragma unroll
      for (int c = 0; c < 32; ++c) t[c] = __builtin_fmaf(a[c]*INV_S3, b[c], t[c]);
    }
  } else {
    const size_t x = wave - 1;
    float a[32], b[32];
    ld_scr<true>(wsN, bd + 0, a);
    ld_scr<true>(wsN, bs + 384 + x*32, b);
#pragma unroll
    for (int c = 0; c < 32; ++c) t[c] = a[c]*b[c];
    ld_scr<true>(wsN, bd + 32 + x*32, a);
    ld_scr<true>(wsN, bs + 480, b);
#pragma unroll
    for (int c = 0; c < 32; ++c) t[c] = __builtin_fmaf(a[c], b[c], t[c]);
  }

  float o[32];
  resblock_g(wave, lane, Wres1, t, o, smem);

  if (wave == 0) {
    float r[32];
    ld_scr<true>(wsN, bd + 128, r);
#pragma unroll
    for (int c = 0; c < 32; ++c) o[c] += r[c];
    if (active) st32f(offs + (size_t)e*32, o);
  } else {
    const int x = wave - 1;
    float r[32];
    ld_scr<true>(wsN, bd + 160 + (size_t)x*32, r);
#pragma unroll
    for (int c = 0; c < 32; ++c) o[c] += r[c];
  }
  __syncthreads();

  const int half = lane >> 5;
  const int lrow = lane & 31;
  const int rows0 = (erows < 32) ? erows : 32;
  const int rows1 = erows - rows0;

  if (wave != 0 && half == 0) {
    const int x = wave - 1;
#pragma unroll
    for (int c = 0; c < 32; ++c) smem[lrow*97 + 3*c + x] = o[c];
  }
  __syncthreads();
  {
    float4* d4 = reinterpret_cast<float4*>(offv + (size_t)eblk*96);
    int tot4 = rows0 * 24;
    for (int i = threadIdx.x; i < tot4; i += 256) {
      int row = (4*i)/96; int r = 4*i - row*96;
      const float* sp = &smem[row*97 + r];
      float4 q; q.x=sp[0]; q.y=sp[1]; q.z=sp[2]; q.w=sp[3];
      d4[i] = q;
    }
  }
  __syncthreads();
  if (wave != 0 && half == 1) {
    const int x = wave - 1;
#pragma unroll
    for (int c = 0; c < 32; ++c) smem[lrow*97 + 3*c + x] = o[c];
  }
  __syncthreads();
  if (rows1 > 0) {
    float4* d4 = reinterpret_cast<float4*>(offv + ((size_t)eblk + 32)*96);
    int tot4 = rows1 * 24;
    for (int i = threadIdx.x; i < tot4; i += 256) {
      int row = (4*i)/96; int r = 4*i - row*96;
      const float* sp = &smem[row*97 + r];
      float4 q; q.x=sp[0]; q.y=sp[1]; q.z=sp[2]; q.w=sp[3];
      d4[i] = q;
    }
  }
}

extern "C" void kernel_launch(void* const* d_in, const int* in_sizes, int n_in,
                              void* d_out, int out_size, void* d_ws, size_t ws_size,
                              hipStream_t stream) {
  const float* node_s = (const float*)d_in[0];
  const float* node_v = (const float*)d_in[1];
  const float* tpw    = (const float*)d_in[2];
  const float* resw   = (const float*)d_in[3];
  const int*   ei     = (const int*)d_in[4];
  const int N = in_sizes[0] / 32;
  const int E = in_sizes[4] / 2;

  float* out  = (float*)d_out;
  float* dgs  = out;
  float* dgv  = out + (size_t)N*32;
  float* offs = out + (size_t)N*128;
  float* offv = offs + (size_t)E*32;

  const size_t need_f32 = (size_t)N * 512 * sizeof(float);
  const int nodeGrid = (N + 63) / 64;
  const int edgeGrid = (E + 63) / 64;

  if (ws_size >= need_f32) {
    node_kernel<false><<<nodeGrid, 256, 0, stream>>>(node_s, node_v, tpw, resw,
                                                     d_ws, dgs, dgv, N);
    edge_kernel_f32<<<edgeGrid, 256, 0, stream>>>(ei, resw, (const float*)d_ws,
                                                  offs, offv, E);
  } else {
    node_kernel<true><<<nodeGrid, 256, 0, stream>>>(node_s, node_v, tpw, resw,
                                                    d_ws, dgs, dgv, N);
    edge_kernel_bf<<<edgeGrid, 256, 0, stream>>>(ei, resw, d_ws, offs, offv, E);
  }
}

// Round 6
// 2002.543 us; speedup vs baseline: 1.4944x; 1.4944x over previous
//
#include <hip/hip_runtime.h>
#include <hip/hip_bf16.h>

#define DEV __device__ __forceinline__

typedef unsigned short u16;
typedef unsigned int u32;

constexpr float INV_C  = 0.17677669529663687f;   // 1/sqrt(32)
constexpr float INV_S3 = 0.5773502691896258f;    // 1/sqrt(3)

DEV float bf2f(u32 h) { return __uint_as_float(h << 16); }
DEV u32 f2bf_bits(float f) {
  u32 u = __float_as_uint(f);
  u += 0x7fffu + ((u >> 16) & 1u);
  return u >> 16;
}

DEV void ld32f(const float* __restrict__ p, float o[32]) {
#pragma unroll
  for (int i = 0; i < 8; ++i) {
    float4 q = reinterpret_cast<const float4*>(p)[i];
    o[4*i+0]=q.x; o[4*i+1]=q.y; o[4*i+2]=q.z; o[4*i+3]=q.w;
  }
}
DEV void st32f(float* __restrict__ p, const float o[32]) {
#pragma unroll
  for (int i = 0; i < 8; ++i) {
    float4 q; q.x=o[4*i+0]; q.y=o[4*i+1]; q.z=o[4*i+2]; q.w=o[4*i+3];
    reinterpret_cast<float4*>(p)[i] = q;
  }
}
DEV void ld32h(const u16* __restrict__ p, float o[32]) {
#pragma unroll
  for (int i = 0; i < 4; ++i) {
    uint4 q = reinterpret_cast<const uint4*>(p)[i];
    u32 w0=q.x, w1=q.y, w2=q.z, w3=q.w;
    o[8*i+0]=bf2f(w0 & 0xffffu); o[8*i+1]=bf2f(w0 >> 16);
    o[8*i+2]=bf2f(w1 & 0xffffu); o[8*i+3]=bf2f(w1 >> 16);
    o[8*i+4]=bf2f(w2 & 0xffffu); o[8*i+5]=bf2f(w2 >> 16);
    o[8*i+6]=bf2f(w3 & 0xffffu); o[8*i+7]=bf2f(w3 >> 16);
  }
}
DEV void st32h(u16* __restrict__ p, const float o[32]) {
#pragma unroll
  for (int i = 0; i < 16; ++i) {
    reinterpret_cast<u32*>(p)[i] = f2bf_bits(o[2*i]) | (f2bf_bits(o[2*i+1]) << 16);
  }
}

template<bool BF>
DEV void ld_scr(const void* __restrict__ ws, size_t off, float o[32]) {
  if (BF) ld32h((const u16*)ws + off, o);
  else    ld32f((const float*)ws + off, o);
}
template<bool BF>
DEV void st_scr(void* __restrict__ ws, size_t off, const float v[32]) {
  if (BF) st32h((u16*)ws + off, v);
  else    st32f((float*)ws + off, v);
}

// out[d] (+)= INV_C * sum_c in[c] * W[c*32+d]
template<bool ACC>
DEV void linT(const float* __restrict__ W, const float in[32], float out[32]) {
  float acc[32];
#pragma unroll
  for (int d = 0; d < 32; ++d) acc[d] = 0.f;
#pragma unroll 4
  for (int c = 0; c < 32; ++c) {
    const float ic = in[c];
#pragma unroll
    for (int d = 0; d < 32; ++d) acc[d] = __builtin_fmaf(ic, W[c*32+d], acc[d]);
  }
#pragma unroll
  for (int d = 0; d < 32; ++d) out[d] = ACC ? __builtin_fmaf(acc[d], INV_C, out[d]) : acc[d]*INV_C;
}
// out[u] = INV_C * sum_v in[v] * W[u*32+v]
DEV void linN(const float* __restrict__ W, const float in[32], float out[32]) {
#pragma unroll 4
  for (int u = 0; u < 32; ++u) {
    float a = 0.f;
#pragma unroll
    for (int v = 0; v < 32; ++v) a = __builtin_fmaf(in[v], W[u*32+v], a);
    out[u] = a * INV_C;
  }
}

DEV float sigmoidf(float x) { return 1.f / (1.f + __expf(-x)); }

// Resblock, wave0 = scalar row, waves1..3 = vector comps. Gate via padded LDS.
// Internal 2-barrier structure: wave0's gsh write happens only after ALL threads
// pass barrier #1, so gsh may alias buffers whose last read precedes the call.
DEV void resblock_g(int wave, int lane, const float* __restrict__ W7,
                    const float in[32], float out[32], float* gsh) {
  float t1[32];
  linT<false>(W7 + (wave==0 ? 0 : 1)*1024, in, t1);     // s1 / v1
  linT<false>(W7 + (wave==0 ? 5 : 6)*1024, in, out);    // skip (in dies here)
  __syncthreads();                                      // barrier #1
  float t2[32];
  if (wave == 0) {
    float g[32];
    linT<false>(W7 + 2*1024, t1, g);                    // gate pre-act
#pragma unroll
    for (int c = 0; c < 32; ++c) gsh[lane*33+c] = sigmoidf(g[c]);
#pragma unroll
    for (int c = 0; c < 32; ++c) t2[c] = t1[c] * sigmoidf(t1[c]);   // silu
  }
  __syncthreads();                                      // barrier #2
  if (wave != 0) {
#pragma unroll
    for (int c = 0; c < 32; ++c) t2[c] = t1[c] * gsh[lane*33+c];
  }
  linT<true>(W7 + (wave==0 ? 3 : 4)*1024, t2, out);     // lin2 accumulate
}

// --- staged-row LDS helpers (rows at stride 34) ---
DEV void rdrow(const float* buf, int lane, float o[32]) {
#pragma unroll
  for (int i = 0; i < 16; ++i) {
    float2 q = *reinterpret_cast<const float2*>(&buf[lane*34 + 2*i]);
    o[2*i] = q.x; o[2*i+1] = q.y;
  }
}
// t = a * row
DEV void mulrow(const float* buf, int lane, const float a[32], float t[32]) {
#pragma unroll
  for (int i = 0; i < 16; ++i) {
    float2 q = *reinterpret_cast<const float2*>(&buf[lane*34 + 2*i]);
    t[2*i] = a[2*i]*q.x; t[2*i+1] = a[2*i+1]*q.y;
  }
}
// t += (row1 * s) * row2
DEV void fma2row(const float* b1, const float* b2, int lane, float s, float t[32]) {
#pragma unroll
  for (int i = 0; i < 16; ++i) {
    float2 u = *reinterpret_cast<const float2*>(&b1[lane*34 + 2*i]);
    float2 v = *reinterpret_cast<const float2*>(&b2[lane*34 + 2*i]);
    t[2*i]   = __builtin_fmaf(u.x*s, v.x, t[2*i]);
    t[2*i+1] = __builtin_fmaf(u.y*s, v.y, t[2*i+1]);
  }
}

// ====================== node kernel: 2-job split ======================
// job0: res3 -> tp0 -> res4 / res5 -> dg_s,dg_v
// job1: res0 -> A, res2 -> R, tp1 -> B*, all into scratch
// Scratch per node (512 elems): A_s@0, A_v@32+32x, R_s@128, R_v@160+32x,
//                               B0@256, Vr1@288+32x, Vr2@384+32x, B3@480
template<bool BF>
__global__ __launch_bounds__(256, 2) void node_kernel(
    const float* __restrict__ node_s, const float* __restrict__ node_v,
    const float* __restrict__ tpw, const float* __restrict__ resw,
    void* __restrict__ wsN,
    float* __restrict__ dgs, float* __restrict__ dgv, int N)
{
  __shared__ float comm[6336];
  float* gsh = comm;
  const int lane = threadIdx.x & 63;
  const int wave = threadIdx.x >> 6;
  const int job  = blockIdx.x & 1;
  const int nblk = (blockIdx.x >> 1) * 64;
  const int n = nblk + lane;
  const bool active = n < N;
  const int nrows = (N - nblk < 64) ? (N - nblk) : 64;

  const float* Wtp0 = tpw;
  const float* Wtp1 = tpw + 4096;

  // stage node_v rows ([n][32][3] f32) coalesced into LDS stride-97 rows
  {
    const float4* s4 = reinterpret_cast<const float4*>(node_v + (size_t)nblk*96);
    int tot4 = nrows * 24;
    for (int i = threadIdx.x; i < tot4; i += 256) {
      int node = (4*i)/96; int r = 4*i - node*96;
      float4 q = s4[i];
      float* dp = &comm[node*97 + r];
      dp[0]=q.x; dp[1]=q.y; dp[2]=q.z; dp[3]=q.w;
    }
  }
  __syncthreads();

  float feat[32];
  if (wave == 0) {
    if (active) ld32f(node_s + (size_t)n*32, feat);
    else {
#pragma unroll
      for (int c = 0; c < 32; ++c) feat[c] = 0.f;
    }
  } else {
    const int x = wave - 1;
    if (active) {
#pragma unroll
      for (int c = 0; c < 32; ++c) feat[c] = comm[lane*97 + 3*c + x];
    } else {
#pragma unroll
      for (int c = 0; c < 32; ++c) feat[c] = 0.f;
    }
  }
  __syncthreads();

  if (job == 0) {
    float dsv[32];
    resblock_g(wave, lane, resw + 3*7168, feat, dsv, gsh);
    __syncthreads();

    float tpo[32];
    if (wave != 0) {
      const int x = wave - 1;
      float vr1[32];
      linN(Wtp0 + 1*1024, feat, vr1);
#pragma unroll
      for (int c = 0; c < 32; ++c) comm[x*2112 + lane*33 + c] = dsv[c]*vr1[c];
    }
    __syncthreads();
    if (wave == 0) {
      float sr0[32];
      linN(Wtp0 + 0*1024, feat, sr0);
#pragma unroll
      for (int c = 0; c < 32; ++c) {
        float a = comm[0*2112+lane*33+c] + comm[1*2112+lane*33+c] + comm[2*2112+lane*33+c];
        tpo[c] = dsv[c]*sr0[c] + a*INV_S3;
      }
      float sr3[32];
      linN(Wtp0 + 3*1024, feat, sr3);
#pragma unroll
      for (int c = 0; c < 32; ++c) comm[0*2112+lane*33+c] = dsv[c];
#pragma unroll
      for (int c = 0; c < 32; ++c) comm[1*2112+lane*33+c] = sr3[c];
    }
    __syncthreads();
    if (wave != 0) {
      float vr2[32];
      linN(Wtp0 + 2*1024, feat, vr2);
#pragma unroll
      for (int c = 0; c < 32; ++c)
        tpo[c] = comm[lane*33+c]*vr2[c] + dsv[c]*comm[2112+lane*33+c];
    }

    float eo[32];
    resblock_g(wave, lane, resw + 4*7168, tpo, eo, gsh);
    {
      float qo[32];
      resblock_g(wave, lane, resw + 5*7168, feat, qo, gsh);
#pragma unroll
      for (int c = 0; c < 32; ++c) eo[c] += qo[c];
    }
    __syncthreads();

    if (wave == 0) {
      if (active) st32f(dgs + (size_t)n*32, eo);
    } else {
      const int x = wave - 1;
#pragma unroll
      for (int c = 0; c < 32; ++c) comm[lane*97 + 3*c + x] = eo[c];
    }
    __syncthreads();
    {
      float4* d4 = reinterpret_cast<float4*>(dgv + (size_t)nblk*96);
      int tot4 = nrows * 24;
      for (int i = threadIdx.x; i < tot4; i += 256) {
        int node = (4*i)/96; int r = 4*i - node*96;
        const float* sp = &comm[node*97 + r];
        float4 q; q.x=sp[0]; q.y=sp[1]; q.z=sp[2]; q.w=sp[3];
        d4[i] = q;
      }
    }
  } else {
    const size_t base = (size_t)n * 512;
    {
      float ao[32];
      resblock_g(wave, lane, resw + 0*7168, feat, ao, gsh);
      if (active) {
        if (wave == 0) st_scr<BF>(wsN, base + 0, ao);
        else           st_scr<BF>(wsN, base + 32 + (size_t)(wave-1)*32, ao);
      }
    }
    {
      float ao[32];
      resblock_g(wave, lane, resw + 2*7168, feat, ao, gsh);
      if (active) {
        if (wave == 0) st_scr<BF>(wsN, base + 128, ao);
        else           st_scr<BF>(wsN, base + 160 + (size_t)(wave-1)*32, ao);
      }
    }
    {
      float b[32];
      if (wave == 0) {
        linN(Wtp1 + 0*1024, feat, b);
        if (active) st_scr<BF>(wsN, base + 256, b);
        linN(Wtp1 + 3*1024, feat, b);
        if (active) st_scr<BF>(wsN, base + 480, b);
      } else {
        const size_t x = wave - 1;
        linN(Wtp1 + 1*1024, feat, b);
        if (active) st_scr<BF>(wsN, base + 288 + x*32, b);
        linN(Wtp1 + 2*1024, feat, b);
        if (active) st_scr<BF>(wsN, base + 384 + x*32, b);
      }
    }
  }
}

// ====================== edge kernel: 3-buffer streamed gather ======================
// Thread t loads 32B of row (edge=t/4, part=t%4) -> 4 lanes cover one 128B row
// contiguously (coalesced). 3 rotating stage buffers: write of stage k+1 never
// touches a buffer read at stages k or k-1 -> one barrier per stage, no WAR race.
// Rows consumed IMMEDIATELY into t (no persistent register arrays besides a0,t).
// B3 pinned in LDS; A_s kept in regs (a0).
#define PREF(P0, P1, base, off) { \
  const float4* _p = reinterpret_cast<const float4*>((base) + (off)); \
  P0 = _p[0]; P1 = _p[1]; }
#define STG(bo, P0, P1) { \
  float* _q = &smem[(bo) + le*34 + lp*8]; \
  reinterpret_cast<float2*>(_q)[0] = make_float2(P0.x, P0.y); \
  reinterpret_cast<float2*>(_q)[1] = make_float2(P0.z, P0.w); \
  reinterpret_cast<float2*>(_q)[2] = make_float2(P1.x, P1.y); \
  reinterpret_cast<float2*>(_q)[3] = make_float2(P1.z, P1.w); }

__global__ __launch_bounds__(256) void edge_kernel_f32(
    const int* __restrict__ ei, const float* __restrict__ resw,
    const float* __restrict__ wsN,
    float* __restrict__ offs, float* __restrict__ offv, int E)
{
  __shared__ float smem[8704];   // SB0@0, SB1@2176, SB2@4352, pinned B3 @6528 (each 64x34)
  __shared__ int eidx[128];      // [0..63]=src, [64..127]=dst
  const int tid  = threadIdx.x;
  const int lane = tid & 63;
  const int wave = tid >> 6;
  const int eblk = blockIdx.x * 64;
  const bool active = (eblk + lane) < E;
  const int erows = (E - eblk < 64) ? (E - eblk) : 64;

  if (tid < 128) {
    int e = eblk + (tid & 63); if (e >= E) e = E - 1;
    eidx[tid] = (tid < 64) ? ei[e] : ei[(size_t)E + e];
  }
  __syncthreads();

  const int le = tid >> 2, lp = tid & 3;
  const float* sb = wsN + (size_t)eidx[le] * 512 + lp * 8;
  const float* db = wsN + (size_t)eidx[64 + le] * 512 + lp * 8;

  float4 Pa0, Pa1, Pb0, Pb1;
  float a0[32], t[32];

  PREF(Pa0, Pa1, sb, 480);                          // s0: B3
  PREF(Pb0, Pb1, db, 0);                            // s1: A_s

  // s0: B3 -> P
  STG(6528, Pa0, Pa1);  PREF(Pa0, Pa1, sb, 256);    // s2: B0
  __syncthreads();
  // s1: A_s -> SB0 ; all waves keep a0
  STG(0, Pb0, Pb1);     PREF(Pb0, Pb1, sb, 384);    // s3: Vr2_0
  __syncthreads();
  rdrow(smem, lane, a0);
  // s2: B0 -> SB1 ; w0: t = a0*B0
  STG(2176, Pa0, Pa1);  PREF(Pa0, Pa1, sb, 416);    // s4: Vr2_1
  __syncthreads();
  if (wave == 0) mulrow(&smem[2176], lane, a0, t);
  // s3: Vr2_0 -> SB2 ; w1: t = a0*Vr2_0
  STG(4352, Pb0, Pb1);  PREF(Pb0, Pb1, sb, 448);    // s5: Vr2_2
  __syncthreads();
  if (wave == 1) mulrow(&smem[4352], lane, a0, t);
  // s4: Vr2_1 -> SB0 ; w2: t = a0*Vr2_1
  STG(0, Pa0, Pa1);     PREF(Pa0, Pa1, sb, 288);    // s6: Vr1_0
  __syncthreads();
  if (wave == 2) mulrow(&smem[0], lane, a0, t);
  // s5: Vr2_2 -> SB1 ; w3: t = a0*Vr2_2 (a0 dies)
  STG(2176, Pb0, Pb1);  PREF(Pb0, Pb1, db, 32);     // s7: A_v0
  __syncthreads();
  if (wave == 3) mulrow(&smem[2176], lane, a0, t);
  // s6: Vr1_0 -> SB2 (no consume)
  STG(4352, Pa0, Pa1);  PREF(Pa0, Pa1, sb, 320);    // s8: Vr1_1
  __syncthreads();
  // s7: A_v0 -> SB0 ; w0: t += A_v0*Vr1_0*IS3 ; w1: t += A_v0*B3
  STG(0, Pb0, Pb1);     PREF(Pb0, Pb1, db, 64);     // s9: A_v1
  __syncthreads();
  if (wave == 0)      fma2row(&smem[0], &smem[4352], lane, INV_S3, t);
  else if (wave == 1) fma2row(&smem[0], &smem[6528], lane, 1.f, t);
  // s8: Vr1_1 -> SB1 (no consume)
  STG(2176, Pa0, Pa1);  PREF(Pa0, Pa1, sb, 352);    // s10: Vr1_2
  __syncthreads();
  // s9: A_v1 -> SB2 ; w0: t += A_v1*Vr1_1*IS3 ; w2: t += A_v1*B3
  STG(4352, Pb0, Pb1);  PREF(Pb0, Pb1, db, 96);     // s11: A_v2
  __syncthreads();
  if (wave == 0)      fma2row(&smem[4352], &smem[2176], lane, INV_S3, t);
  else if (wave == 2) fma2row(&smem[4352], &smem[6528], lane, 1.f, t);
  // s10: Vr1_2 -> SB0 (no consume)
  STG(0, Pa0, Pa1);
  __syncthreads();
  // s11: A_v2 -> SB1 ; w0: t += A_v2*Vr1_2*IS3 ; w3: t += A_v2*B3
  STG(2176, Pb0, Pb1);
  __syncthreads();
  if (wave == 0)      fma2row(&smem[2176], &smem[0], lane, INV_S3, t);
  else if (wave == 3) fma2row(&smem[2176], &smem[6528], lane, 1.f, t);
  // resblock barrier #1 orders the stage-buffer reads above vs. gate writes below

  float o[32];
  resblock_g(wave, lane, resw + 1*7168, t, o, smem);

  // R[dst] direct per-lane + add (+ scalar-part store)
  {
    const float* drow = wsN + (size_t)eidx[64 + lane] * 512;
    float r[32];
    if (wave == 0) {
      ld32f(drow + 128, r);
#pragma unroll
      for (int c = 0; c < 32; ++c) o[c] += r[c];
      if (active) st32f(offs + (size_t)(eblk + lane)*32, o);
    } else {
      ld32f(drow + 160 + (size_t)(wave - 1)*32, r);
#pragma unroll
      for (int c = 0; c < 32; ++c) o[c] += r[c];
    }
  }
  __syncthreads();   // gate reads done; smem reused as output staging

  const int half = lane >> 5;
  const int lrow = lane & 31;
  const int rows0 = (erows < 32) ? erows : 32;
  const int rows1 = erows - rows0;

  if (wave != 0 && half == 0) {
    const int x = wave - 1;
#pragma unroll
    for (int c = 0; c < 32; ++c) smem[lrow*97 + 3*c + x] = o[c];
  }
  __syncthreads();
  {
    float4* d4 = reinterpret_cast<float4*>(offv + (size_t)eblk*96);
    int tot4 = rows0 * 24;
    for (int i = threadIdx.x; i < tot4; i += 256) {
      int row = (4*i)/96; int r = 4*i - row*96;
      const float* sp = &smem[row*97 + r];
      float4 q; q.x=sp[0]; q.y=sp[1]; q.z=sp[2]; q.w=sp[3];
      d4[i] = q;
    }
  }
  __syncthreads();
  if (wave != 0 && half == 1) {
    const int x = wave - 1;
#pragma unroll
    for (int c = 0; c < 32; ++c) smem[lrow*97 + 3*c + x] = o[c];
  }
  __syncthreads();
  if (rows1 > 0) {
    float4* d4 = reinterpret_cast<float4*>(offv + ((size_t)eblk + 32)*96);
    int tot4 = rows1 * 24;
    for (int i = threadIdx.x; i < tot4; i += 256) {
      int row = (4*i)/96; int r = 4*i - row*96;
      const float* sp = &smem[row*97 + r];
      float4 q; q.x=sp[0]; q.y=sp[1]; q.z=sp[2]; q.w=sp[3];
      d4[i] = q;
    }
  }
}

// bf16-scratch fallback edge kernel (only if ws too small for f32 scratch)
__global__ __launch_bounds__(256, 2) void edge_kernel_bf(
    const int* __restrict__ ei, const float* __restrict__ resw,
    const void* __restrict__ wsN,
    float* __restrict__ offs, float* __restrict__ offv, int E)
{
  __shared__ float smem[3104];
  const int lane = threadIdx.x & 63;
  const int wave = threadIdx.x >> 6;
  const int eblk = blockIdx.x * 64;
  const int e = eblk + lane;
  const bool active = e < E;
  const int erows = (E - eblk < 64) ? (E - eblk) : 64;
  int src = 0, dst = 0;
  if (active) { src = ei[e]; dst = ei[E + e]; }
  const size_t bs = (size_t)src * 512;
  const size_t bd = (size_t)dst * 512;

  float t[32];
  if (wave == 0) {
    float a[32], b[32];
    ld_scr<true>(wsN, bd + 0, a);
    ld_scr<true>(wsN, bs + 256, b);
#pragma unroll
    for (int c = 0; c < 32; ++c) t[c] = a[c]*b[c];
#pragma unroll
    for (int x = 0; x < 3; ++x) {
      ld_scr<true>(wsN, bd + 32 + (size_t)x*32, a);
      ld_scr<true>(wsN, bs + 288 + (size_t)x*32, b);
#pragma unroll
      for (int c = 0; c < 32; ++c) t[c] = __builtin_fmaf(a[c]*INV_S3, b[c], t[c]);
    }
  } else {
    const size_t x = wave - 1;
    float a[32], b[32];
    ld_scr<true>(wsN, bd + 0, a);
    ld_scr<true>(wsN, bs + 384 + x*32, b);
#pragma unroll
    for (int c = 0; c < 32; ++c) t[c] = a[c]*b[c];
    ld_scr<true>(wsN, bd + 32 + x*32, a);
    ld_scr<true>(wsN, bs + 480, b);
#pragma unroll
    for (int c = 0; c < 32; ++c) t[c] = __builtin_fmaf(a[c], b[c], t[c]);
  }

  float o[32];
  resblock_g(wave, lane, resw + 1*7168, t, o, smem);

  if (wave == 0) {
    float r[32];
    ld_scr<true>(wsN, bd + 128, r);
#pragma unroll
    for (int c = 0; c < 32; ++c) o[c] += r[c];
    if (active) st32f(offs + (size_t)e*32, o);
  } else {
    const int x = wave - 1;
    float r[32];
    ld_scr<true>(wsN, bd + 160 + (size_t)x*32, r);
#pragma unroll
    for (int c = 0; c < 32; ++c) o[c] += r[c];
  }
  __syncthreads();

  const int half = lane >> 5;
  const int lrow = lane & 31;
  const int rows0 = (erows < 32) ? erows : 32;
  const int rows1 = erows - rows0;

  if (wave != 0 && half == 0) {
    const int x = wave - 1;
#pragma unroll
    for (int c = 0; c < 32; ++c) smem[lrow*97 + 3*c + x] = o[c];
  }
  __syncthreads();
  {
    float4* d4 = reinterpret_cast<float4*>(offv + (size_t)eblk*96);
    int tot4 = rows0 * 24;
    for (int i = threadIdx.x; i < tot4; i += 256) {
      int row = (4*i)/96; int r = 4*i - row*96;
      const float* sp = &smem[row*97 + r];
      float4 q; q.x=sp[0]; q.y=sp[1]; q.z=sp[2]; q.w=sp[3];
      d4[i] = q;
    }
  }
  __syncthreads();
  if (wave != 0 && half == 1) {
    const int x = wave - 1;
#pragma unroll
    for (int c = 0; c < 32; ++c) smem[lrow*97 + 3*c + x] = o[c];
  }
  __syncthreads();
  if (rows1 > 0) {
    float4* d4 = reinterpret_cast<float4*>(offv + ((size_t)eblk + 32)*96);
    int tot4 = rows1 * 24;
    for (int i = threadIdx.x; i < tot4; i += 256) {
      int row = (4*i)/96; int r = 4*i - row*96;
      const float* sp = &smem[row*97 + r];
      float4 q; q.x=sp[0]; q.y=sp[1]; q.z=sp[2]; q.w=sp[3];
      d4[i] = q;
    }
  }
}

extern "C" void kernel_launch(void* const* d_in, const int* in_sizes, int n_in,
                              void* d_out, int out_size, void* d_ws, size_t ws_size,
                              hipStream_t stream) {
  const float* node_s = (const float*)d_in[0];
  const float* node_v = (const float*)d_in[1];
  const float* tpw    = (const float*)d_in[2];
  const float* resw   = (const float*)d_in[3];
  const int*   ei     = (const int*)d_in[4];
  const int N = in_sizes[0] / 32;
  const int E = in_sizes[4] / 2;

  float* out  = (float*)d_out;
  float* dgs  = out;
  float* dgv  = out + (size_t)N*32;
  float* offs = out + (size_t)N*128;
  float* offv = offs + (size_t)E*32;

  const size_t need_f32 = (size_t)N * 512 * sizeof(float);
  const int nodeGrid = 2 * ((N + 63) / 64);   // 2 jobs per 64-node block
  const int edgeGrid = (E + 63) / 64;

  if (ws_size >= need_f32) {
    node_kernel<false><<<nodeGrid, 256, 0, stream>>>(node_s, node_v, tpw, resw,
                                                     d_ws, dgs, dgv, N);
    edge_kernel_f32<<<edgeGrid, 256, 0, stream>>>(ei, resw, (const float*)d_ws,
                                                  offs, offv, E);
  } else {
    node_kernel<true><<<nodeGrid, 256, 0, stream>>>(node_s, node_v, tpw, resw,
                                                    d_ws, dgs, dgv, N);
    edge_kernel_bf<<<edgeGrid, 256, 0, stream>>>(ei, resw, d_ws, offs, offv, E);
  }
}

// Round 7
// 1842.362 us; speedup vs baseline: 1.6243x; 1.0869x over previous
//
#include <hip/hip_runtime.h>
#include <hip/hip_bf16.h>

#define DEV __device__ __forceinline__

typedef unsigned short u16;
typedef unsigned int u32;

constexpr float INV_C  = 0.17677669529663687f;   // 1/sqrt(32)
constexpr float INV_S3 = 0.5773502691896258f;    // 1/sqrt(3)

DEV float bf2f(u32 h) { return __uint_as_float(h << 16); }
DEV u32 f2bf_bits(float f) {
  u32 u = __float_as_uint(f);
  u += 0x7fffu + ((u >> 16) & 1u);
  return u >> 16;
}

DEV void ld32f(const float* __restrict__ p, float o[32]) {
#pragma unroll
  for (int i = 0; i < 8; ++i) {
    float4 q = reinterpret_cast<const float4*>(p)[i];
    o[4*i+0]=q.x; o[4*i+1]=q.y; o[4*i+2]=q.z; o[4*i+3]=q.w;
  }
}
DEV void st32f(float* __restrict__ p, const float o[32]) {
#pragma unroll
  for (int i = 0; i < 8; ++i) {
    float4 q; q.x=o[4*i+0]; q.y=o[4*i+1]; q.z=o[4*i+2]; q.w=o[4*i+3];
    reinterpret_cast<float4*>(p)[i] = q;
  }
}
DEV void ld32h(const u16* __restrict__ p, float o[32]) {
#pragma unroll
  for (int i = 0; i < 4; ++i) {
    uint4 q = reinterpret_cast<const uint4*>(p)[i];
    u32 w0=q.x, w1=q.y, w2=q.z, w3=q.w;
    o[8*i+0]=bf2f(w0 & 0xffffu); o[8*i+1]=bf2f(w0 >> 16);
    o[8*i+2]=bf2f(w1 & 0xffffu); o[8*i+3]=bf2f(w1 >> 16);
    o[8*i+4]=bf2f(w2 & 0xffffu); o[8*i+5]=bf2f(w2 >> 16);
    o[8*i+6]=bf2f(w3 & 0xffffu); o[8*i+7]=bf2f(w3 >> 16);
  }
}
DEV void st32h(u16* __restrict__ p, const float o[32]) {
#pragma unroll
  for (int i = 0; i < 16; ++i) {
    reinterpret_cast<u32*>(p)[i] = f2bf_bits(o[2*i]) | (f2bf_bits(o[2*i+1]) << 16);
  }
}

template<bool BF>
DEV void ld_scr(const void* __restrict__ ws, size_t off, float o[32]) {
  if (BF) ld32h((const u16*)ws + off, o);
  else    ld32f((const float*)ws + off, o);
}
template<bool BF>
DEV void st_scr(void* __restrict__ ws, size_t off, const float v[32]) {
  if (BF) st32h((u16*)ws + off, v);
  else    st32f((float*)ws + off, v);
}

// out[d] (+)= INV_C * sum_c in[c] * W[c*32+d]   (weights via SGPR path)
template<bool ACC>
DEV void linT(const float* __restrict__ W, const float in[32], float out[32]) {
  float acc[32];
#pragma unroll
  for (int d = 0; d < 32; ++d) acc[d] = 0.f;
#pragma unroll 4
  for (int c = 0; c < 32; ++c) {
    const float ic = in[c];
#pragma unroll
    for (int d = 0; d < 32; ++d) acc[d] = __builtin_fmaf(ic, W[c*32+d], acc[d]);
  }
#pragma unroll
  for (int d = 0; d < 32; ++d) out[d] = ACC ? __builtin_fmaf(acc[d], INV_C, out[d]) : acc[d]*INV_C;
}
// out[u] = INV_C * sum_v in[v] * W[u*32+v]
DEV void linN(const float* __restrict__ W, const float in[32], float out[32]) {
#pragma unroll 4
  for (int u = 0; u < 32; ++u) {
    float a = 0.f;
#pragma unroll
    for (int v = 0; v < 32; ++v) a = __builtin_fmaf(in[v], W[u*32+v], a);
    out[u] = a * INV_C;
  }
}

DEV float sigmoidf(float x) { return 1.f / (1.f + __expf(-x)); }

// Resblock (node kernel path), wave0 = scalar row, waves1..3 = vector comps.
DEV void resblock_g(int wave, int lane, const float* __restrict__ W7,
                    const float in[32], float out[32], float* gsh) {
  float t1[32];
  linT<false>(W7 + (wave==0 ? 0 : 1)*1024, in, t1);     // s1 / v1
  linT<false>(W7 + (wave==0 ? 5 : 6)*1024, in, out);    // skip
  __syncthreads();                                      // barrier #1
  float t2[32];
  if (wave == 0) {
    float g[32];
    linT<false>(W7 + 2*1024, t1, g);                    // gate pre-act
#pragma unroll
    for (int c = 0; c < 32; ++c) gsh[lane*33+c] = sigmoidf(g[c]);
#pragma unroll
    for (int c = 0; c < 32; ++c) t2[c] = t1[c] * sigmoidf(t1[c]);   // silu
  }
  __syncthreads();                                      // barrier #2
  if (wave != 0) {
#pragma unroll
    for (int c = 0; c < 32; ++c) t2[c] = t1[c] * gsh[lane*33+c];
  }
  linT<true>(W7 + (wave==0 ? 3 : 4)*1024, t2, out);     // lin2 accumulate
}

// ---- LDS-weight mat-vecs for the wave-private edge kernel ----
// out[d] (+)= INV_C * sum_c in[c] * W[c*32+d], W points into LDS (per-lane base OK)
template<bool ACC>
DEV void matW(const float* W, const float in[32], float out[32]) {
  float acc[32];
#pragma unroll
  for (int d = 0; d < 32; ++d) acc[d] = 0.f;
#pragma unroll 2
  for (int c = 0; c < 32; ++c) {
    const float ic = in[c];
#pragma unroll
    for (int i = 0; i < 8; ++i) {
      float4 w = *reinterpret_cast<const float4*>(&W[c*32 + i*4]);
      acc[4*i+0] = __builtin_fmaf(ic, w.x, acc[4*i+0]);
      acc[4*i+1] = __builtin_fmaf(ic, w.y, acc[4*i+1]);
      acc[4*i+2] = __builtin_fmaf(ic, w.z, acc[4*i+2]);
      acc[4*i+3] = __builtin_fmaf(ic, w.w, acc[4*i+3]);
    }
  }
#pragma unroll
  for (int d = 0; d < 32; ++d)
    out[d] = ACC ? __builtin_fmaf(acc[d], INV_C, out[d]) : acc[d]*INV_C;
}
// dual: o1 = Wa^T in, o2 = Wb^T in (both * INV_C), one pass over in
DEV void matW2(const float* Wa, const float* Wb, const float in[32],
               float o1[32], float o2[32]) {
  float a1[32], a2[32];
#pragma unroll
  for (int d = 0; d < 32; ++d) { a1[d] = 0.f; a2[d] = 0.f; }
#pragma unroll 2
  for (int c = 0; c < 32; ++c) {
    const float ic = in[c];
#pragma unroll
    for (int i = 0; i < 8; ++i) {
      float4 w = *reinterpret_cast<const float4*>(&Wa[c*32 + i*4]);
      a1[4*i+0] = __builtin_fmaf(ic, w.x, a1[4*i+0]);
      a1[4*i+1] = __builtin_fmaf(ic, w.y, a1[4*i+1]);
      a1[4*i+2] = __builtin_fmaf(ic, w.z, a1[4*i+2]);
      a1[4*i+3] = __builtin_fmaf(ic, w.w, a1[4*i+3]);
    }
#pragma unroll
    for (int i = 0; i < 8; ++i) {
      float4 w = *reinterpret_cast<const float4*>(&Wb[c*32 + i*4]);
      a2[4*i+0] = __builtin_fmaf(ic, w.x, a2[4*i+0]);
      a2[4*i+1] = __builtin_fmaf(ic, w.y, a2[4*i+1]);
      a2[4*i+2] = __builtin_fmaf(ic, w.z, a2[4*i+2]);
      a2[4*i+3] = __builtin_fmaf(ic, w.w, a2[4*i+3]);
    }
  }
#pragma unroll
  for (int d = 0; d < 32; ++d) { o1[d] = a1[d]*INV_C; o2[d] = a2[d]*INV_C; }
}

// ====================== node kernel (unchanged from round 6) ======================
template<bool BF>
__global__ __launch_bounds__(256, 2) void node_kernel(
    const float* __restrict__ node_s, const float* __restrict__ node_v,
    const float* __restrict__ tpw, const float* __restrict__ resw,
    void* __restrict__ wsN,
    float* __restrict__ dgs, float* __restrict__ dgv, int N)
{
  __shared__ float comm[6336];
  float* gsh = comm;
  const int lane = threadIdx.x & 63;
  const int wave = threadIdx.x >> 6;
  const int job  = blockIdx.x & 1;
  const int nblk = (blockIdx.x >> 1) * 64;
  const int n = nblk + lane;
  const bool active = n < N;
  const int nrows = (N - nblk < 64) ? (N - nblk) : 64;

  const float* Wtp0 = tpw;
  const float* Wtp1 = tpw + 4096;

  {
    const float4* s4 = reinterpret_cast<const float4*>(node_v + (size_t)nblk*96);
    int tot4 = nrows * 24;
    for (int i = threadIdx.x; i < tot4; i += 256) {
      int node = (4*i)/96; int r = 4*i - node*96;
      float4 q = s4[i];
      float* dp = &comm[node*97 + r];
      dp[0]=q.x; dp[1]=q.y; dp[2]=q.z; dp[3]=q.w;
    }
  }
  __syncthreads();

  float feat[32];
  if (wave == 0) {
    if (active) ld32f(node_s + (size_t)n*32, feat);
    else {
#pragma unroll
      for (int c = 0; c < 32; ++c) feat[c] = 0.f;
    }
  } else {
    const int x = wave - 1;
    if (active) {
#pragma unroll
      for (int c = 0; c < 32; ++c) feat[c] = comm[lane*97 + 3*c + x];
    } else {
#pragma unroll
      for (int c = 0; c < 32; ++c) feat[c] = 0.f;
    }
  }
  __syncthreads();

  if (job == 0) {
    float dsv[32];
    resblock_g(wave, lane, resw + 3*7168, feat, dsv, gsh);
    __syncthreads();

    float tpo[32];
    if (wave != 0) {
      const int x = wave - 1;
      float vr1[32];
      linN(Wtp0 + 1*1024, feat, vr1);
#pragma unroll
      for (int c = 0; c < 32; ++c) comm[x*2112 + lane*33 + c] = dsv[c]*vr1[c];
    }
    __syncthreads();
    if (wave == 0) {
      float sr0[32];
      linN(Wtp0 + 0*1024, feat, sr0);
#pragma unroll
      for (int c = 0; c < 32; ++c) {
        float a = comm[0*2112+lane*33+c] + comm[1*2112+lane*33+c] + comm[2*2112+lane*33+c];
        tpo[c] = dsv[c]*sr0[c] + a*INV_S3;
      }
      float sr3[32];
      linN(Wtp0 + 3*1024, feat, sr3);
#pragma unroll
      for (int c = 0; c < 32; ++c) comm[0*2112+lane*33+c] = dsv[c];
#pragma unroll
      for (int c = 0; c < 32; ++c) comm[1*2112+lane*33+c] = sr3[c];
    }
    __syncthreads();
    if (wave != 0) {
      float vr2[32];
      linN(Wtp0 + 2*1024, feat, vr2);
#pragma unroll
      for (int c = 0; c < 32; ++c)
        tpo[c] = comm[lane*33+c]*vr2[c] + dsv[c]*comm[2112+lane*33+c];
    }

    float eo[32];
    resblock_g(wave, lane, resw + 4*7168, tpo, eo, gsh);
    {
      float qo[32];
      resblock_g(wave, lane, resw + 5*7168, feat, qo, gsh);
#pragma unroll
      for (int c = 0; c < 32; ++c) eo[c] += qo[c];
    }
    __syncthreads();

    if (wave == 0) {
      if (active) st32f(dgs + (size_t)n*32, eo);
    } else {
      const int x = wave - 1;
#pragma unroll
      for (int c = 0; c < 32; ++c) comm[lane*97 + 3*c + x] = eo[c];
    }
    __syncthreads();
    {
      float4* d4 = reinterpret_cast<float4*>(dgv + (size_t)nblk*96);
      int tot4 = nrows * 24;
      for (int i = threadIdx.x; i < tot4; i += 256) {
        int node = (4*i)/96; int r = 4*i - node*96;
        const float* sp = &comm[node*97 + r];
        float4 q; q.x=sp[0]; q.y=sp[1]; q.z=sp[2]; q.w=sp[3];
        d4[i] = q;
      }
    }
  } else {
    const size_t base = (size_t)n * 512;
    {
      float ao[32];
      resblock_g(wave, lane, resw + 0*7168, feat, ao, gsh);
      if (active) {
        if (wave == 0) st_scr<BF>(wsN, base + 0, ao);
        else           st_scr<BF>(wsN, base + 32 + (size_t)(wave-1)*32, ao);
      }
    }
    {
      float ao[32];
      resblock_g(wave, lane, resw + 2*7168, feat, ao, gsh);
      if (active) {
        if (wave == 0) st_scr<BF>(wsN, base + 128, ao);
        else           st_scr<BF>(wsN, base + 160 + (size_t)(wave-1)*32, ao);
      }
    }
    {
      float b[32];
      if (wave == 0) {
        linN(Wtp1 + 0*1024, feat, b);
        if (active) st_scr<BF>(wsN, base + 256, b);
        linN(Wtp1 + 3*1024, feat, b);
        if (active) st_scr<BF>(wsN, base + 480, b);
      } else {
        const size_t x = wave - 1;
        linN(Wtp1 + 1*1024, feat, b);
        if (active) st_scr<BF>(wsN, base + 288 + x*32, b);
        linN(Wtp1 + 2*1024, feat, b);
        if (active) st_scr<BF>(wsN, base + 384 + x*32, b);
      }
    }
  }
}

// ============ edge kernel: wave-private, zero-barrier, LDS weights ============
// lane = (edge, comp): comp = lane&3 (0=scalar, 1..3 = x,y,z), 16 edges/wave.
// Weights (res_w[1], 28KB) staged to LDS once; gate crosses comps via __shfl.
// After the initial stage there are NO __syncthreads: waves run free, grid-stride.
__global__ __launch_bounds__(256, 3) void edge_kernel_f32(
    const int* __restrict__ ei, const float* __restrict__ resw,
    const float* __restrict__ wsN,
    float* __restrict__ offs, float* __restrict__ offv, int E, int ntiles)
{
  __shared__ float wsh[7168];
  {
    const float4* s4 = reinterpret_cast<const float4*>(resw + 7168);
    float4* d4 = reinterpret_cast<float4*>(wsh);
    for (int i = threadIdx.x; i < 1792; i += 256) d4[i] = s4[i];
  }
  __syncthreads();   // the only barrier

  const int lane = threadIdx.x & 63;
  const int wave = threadIdx.x >> 6;
  const int comp = lane & 3;
  const int eloc = lane >> 2;
  const bool is_s = (comp == 0);
  const int x = comp - 1;            // valid for v-lanes

  const float* W1  = wsh + (is_s ? 0 : 1)*1024;   // s1 / v1
  const float* W2  = wsh + 2*1024;                // gate
  const float* Wl2 = wsh + (is_s ? 3 : 4)*1024;   // lin2
  const float* Wsk = wsh + (is_s ? 5 : 6)*1024;   // skip

  const int wid = blockIdx.x*4 + wave;
  const int wstride = gridDim.x*4;

  for (int tile = wid; tile < ntiles; tile += wstride) {
    const int e = tile*16 + eloc;
    const bool eact = e < E;
    const int ec = eact ? e : (E - 1);
    const int sn = ei[ec], dn = ei[(size_t)E + ec];
    const float* S = wsN + (size_t)sn * 512;
    const float* D = wsN + (size_t)dn * 512;

    // ---- TP combine (streamed, register-light) ----
    float t[32];
    {
      const float4* a4 = reinterpret_cast<const float4*>(D);                 // A_s[dst]
      const float4* b4 = reinterpret_cast<const float4*>(
          is_s ? S + 256 : S + 384 + (size_t)x*32);                          // B0 | Vr2_x
#pragma unroll
      for (int i = 0; i < 8; ++i) {
        float4 a = a4[i], b = b4[i];
        t[4*i+0] = a.x*b.x; t[4*i+1] = a.y*b.y; t[4*i+2] = a.z*b.z; t[4*i+3] = a.w*b.w;
      }
    }
#pragma unroll
    for (int xx = 0; xx < 3; ++xx) {
      if (is_s || comp == xx+1) {
        const float4* a4 = reinterpret_cast<const float4*>(D + 32 + xx*32);  // A_v[dst][xx]
        const float4* b4 = reinterpret_cast<const float4*>(
            is_s ? S + 288 + xx*32 : S + 480);                               // Vr1_xx | B3
        const float sc = is_s ? INV_S3 : 1.f;
#pragma unroll
        for (int i = 0; i < 8; ++i) {
          float4 a = a4[i], b = b4[i];
          t[4*i+0] = __builtin_fmaf(a.x*sc, b.x, t[4*i+0]);
          t[4*i+1] = __builtin_fmaf(a.y*sc, b.y, t[4*i+1]);
          t[4*i+2] = __builtin_fmaf(a.z*sc, b.z, t[4*i+2]);
          t[4*i+3] = __builtin_fmaf(a.w*sc, b.w, t[4*i+3]);
        }
      }
    }

    // ---- resblock res_w[1] ----
    float t1[32], o[32];
    matW2(W1, Wsk, t, t1, o);            // t1 = s1|v1, o = skip

    float sg[32];
    if (is_s) {
      float g[32];
      matW<false>(W2, t1, g);
#pragma unroll
      for (int c = 0; c < 32; ++c) sg[c] = sigmoidf(g[c]);
    } else {
#pragma unroll
      for (int c = 0; c < 32; ++c) sg[c] = 0.f;
    }

    float t2[32];
    const int gsrc = lane & 60;          // comp-0 lane of this edge
#pragma unroll
    for (int c = 0; c < 32; ++c) {
      float gv = __shfl(sg[c], gsrc);
      t2[c] = is_s ? t1[c]*sigmoidf(t1[c]) : t1[c]*gv;
    }
    matW<true>(Wl2, t2, o);              // o += lin2

    // ---- + R[dst] ----
    {
      const float4* r4 = reinterpret_cast<const float4*>(
          is_s ? D + 128 : D + 160 + (size_t)x*32);
#pragma unroll
      for (int i = 0; i < 8; ++i) {
        float4 r = r4[i];
        o[4*i+0] += r.x; o[4*i+1] += r.y; o[4*i+2] += r.z; o[4*i+3] += r.w;
      }
    }

    // ---- store ----
    if (eact) {
      if (is_s) {
        st32f(offs + (size_t)e*32, o);
      } else {
        float* base = offv + (size_t)e*96 + x;
#pragma unroll
        for (int c = 0; c < 32; ++c) base[c*3] = o[c];
      }
    }
  }
}

// bf16-scratch fallback edge kernel (only if ws too small for f32 scratch)
__global__ __launch_bounds__(256, 2) void edge_kernel_bf(
    const int* __restrict__ ei, const float* __restrict__ resw,
    const void* __restrict__ wsN,
    float* __restrict__ offs, float* __restrict__ offv, int E)
{
  __shared__ float smem[3104];
  const int lane = threadIdx.x & 63;
  const int wave = threadIdx.x >> 6;
  const int eblk = blockIdx.x * 64;
  const int e = eblk + lane;
  const bool active = e < E;
  const int erows = (E - eblk < 64) ? (E - eblk) : 64;
  int src = 0, dst = 0;
  if (active) { src = ei[e]; dst = ei[E + e]; }
  const size_t bs = (size_t)src * 512;
  const size_t bd = (size_t)dst * 512;

  float t[32];
  if (wave == 0) {
    float a[32], b[32];
    ld_scr<true>(wsN, bd + 0, a);
    ld_scr<true>(wsN, bs + 256, b);
#pragma unroll
    for (int c = 0; c < 32; ++c) t[c] = a[c]*b[c];
#pragma unroll
    for (int x = 0; x < 3; ++x) {
      ld_scr<true>(wsN, bd + 32 + (size_t)x*32, a);
      ld_scr<true>(wsN, bs + 288 + (size_t)x*32, b);
#pragma unroll
      for (int c = 0; c < 32; ++c) t[c] = __builtin_fmaf(a[c]*INV_S3, b[c], t[c]);
    }
  } else {
    const size_t x = wave - 1;
    float a[32], b[32];
    ld_scr<true>(wsN, bd + 0, a);
    ld_scr<true>(wsN, bs + 384 + x*32, b);
#pragma unroll
    for (int c = 0; c < 32; ++c) t[c] = a[c]*b[c];
    ld_scr<true>(wsN, bd + 32 + x*32, a);
    ld_scr<true>(wsN, bs + 480, b);
#pragma unroll
    for (int c = 0; c < 32; ++c) t[c] = __builtin_fmaf(a[c], b[c], t[c]);
  }

  float o[32];
  resblock_g(wave, lane, resw + 1*7168, t, o, smem);

  if (wave == 0) {
    float r[32];
    ld_scr<true>(wsN, bd + 128, r);
#pragma unroll
    for (int c = 0; c < 32; ++c) o[c] += r[c];
    if (active) st32f(offs + (size_t)e*32, o);
  } else {
    const int x = wave - 1;
    float r[32];
    ld_scr<true>(wsN, bd + 160 + (size_t)x*32, r);
#pragma unroll
    for (int c = 0; c < 32; ++c) o[c] += r[c];
  }
  __syncthreads();

  const int half = lane >> 5;
  const int lrow = lane & 31;
  const int rows0 = (erows < 32) ? erows : 32;
  const int rows1 = erows - rows0;

  if (wave != 0 && half == 0) {
    const int x = wave - 1;
#pragma unroll
    for (int c = 0; c < 32; ++c) smem[lrow*97 + 3*c + x] = o[c];
  }
  __syncthreads();
  {
    float4* d4 = reinterpret_cast<float4*>(offv + (size_t)eblk*96);
    int tot4 = rows0 * 24;
    for (int i = threadIdx.x; i < tot4; i += 256) {
      int row = (4*i)/96; int r = 4*i - row*96;
      const float* sp = &smem[row*97 + r];
      float4 q; q.x=sp[0]; q.y=sp[1]; q.z=sp[2]; q.w=sp[3];
      d4[i] = q;
    }
  }
  __syncthreads();
  if (wave != 0 && half == 1) {
    const int x = wave - 1;
#pragma unroll
    for (int c = 0; c < 32; ++c) smem[lrow*97 + 3*c + x] = o[c];
  }
  __syncthreads();
  if (rows1 > 0) {
    float4* d4 = reinterpret_cast<float4*>(offv + ((size_t)eblk + 32)*96);
    int tot4 = rows1 * 24;
    for (int i = threadIdx.x; i < tot4; i += 256) {
      int row = (4*i)/96; int r = 4*i - row*96;
      const float* sp = &smem[row*97 + r];
      float4 q; q.x=sp[0]; q.y=sp[1]; q.z=sp[2]; q.w=sp[3];
      d4[i] = q;
    }
  }
}

extern "C" void kernel_launch(void* const* d_in, const int* in_sizes, int n_in,
                              void* d_out, int out_size, void* d_ws, size_t ws_size,
                              hipStream_t stream) {
  const float* node_s = (const float*)d_in[0];
  const float* node_v = (const float*)d_in[1];
  const float* tpw    = (const float*)d_in[2];
  const float* resw   = (const float*)d_in[3];
  const int*   ei     = (const int*)d_in[4];
  const int N = in_sizes[0] / 32;
  const int E = in_sizes[4] / 2;

  float* out  = (float*)d_out;
  float* dgs  = out;
  float* dgv  = out + (size_t)N*32;
  float* offs = out + (size_t)N*128;
  float* offv = offs + (size_t)E*32;

  const size_t need_f32 = (size_t)N * 512 * sizeof(float);
  const int nodeGrid = 2 * ((N + 63) / 64);
  const int ntiles = (E + 15) / 16;

  if (ws_size >= need_f32) {
    node_kernel<false><<<nodeGrid, 256, 0, stream>>>(node_s, node_v, tpw, resw,
                                                     d_ws, dgs, dgv, N);
    int eg = (ntiles + 3) / 4; if (eg > 1024) eg = 1024;
    edge_kernel_f32<<<eg, 256, 0, stream>>>(ei, resw, (const float*)d_ws,
                                            offs, offv, E, ntiles);
  } else {
    node_kernel<true><<<nodeGrid, 256, 0, stream>>>(node_s, node_v, tpw, resw,
                                                    d_ws, dgs, dgv, N);
    edge_kernel_bf<<<(E + 63)/64, 256, 0, stream>>>(ei, resw, d_ws, offs, offv, E);
  }
}